// Round 6
// baseline (66.834 us; speedup 1.0000x reference)
//
#include <hip/hip_runtime.h>
#include <math.h>

#define BLOCK 256
#define PPT   2                 // points per thread

typedef _Float16 half2v __attribute__((ext_vector_type(2)));
typedef _Float16 half4v __attribute__((ext_vector_type(4)));
typedef float    float4v __attribute__((ext_vector_type(4)));

__device__ __forceinline__ half2v cvt_pk_h2(float a, float b) {
    return __builtin_bit_cast(half2v, __builtin_amdgcn_cvt_pkrtz(a, b));
}

#define H4(x) {(_Float16)(x), (_Float16)(x), (_Float16)(x), (_Float16)(x)}

// Packed-fp16 tanh: odd poly t*p(t^2), deg-5 in s, fit on s in [0,9], clamp
// |x|<=3, endpoint lifted so saturated units land on exactly +-1.0.
__device__ __forceinline__ half4v tanh_pk4(half4v x) {
    const half4v c5 = H4(-3.71625e-05f);
    const half4v c4 = H4( 1.09648e-03f);
    const half4v c3 = H4(-1.288264e-02f);
    const half4v c2 = H4( 7.941906e-02f);
    const half4v c1 = H4(-3.0042735e-01f);
    const half4v c0 = H4( 9.9607644e-01f);
    const half4v hi = H4( 3.0f);
    const half4v lo = H4(-3.0f);
    half4v t = __builtin_elementwise_min(__builtin_elementwise_max(x, lo), hi);
    half4v s = t * t;
#if __has_builtin(__builtin_elementwise_fma)
    half4v p = __builtin_elementwise_fma(c5, s, c4);
    p = __builtin_elementwise_fma(p, s, c3);
    p = __builtin_elementwise_fma(p, s, c2);
    p = __builtin_elementwise_fma(p, s, c1);
    p = __builtin_elementwise_fma(p, s, c0);
#else
    half4v p = c5 * s + c4;
    p = p * s + c3;
    p = p * s + c2;
    p = p * s + c1;
    p = p * s + c0;
#endif
    return t * p;
}

__device__ __forceinline__ half4v pk4_from_f32(float a, float b, float c, float d) {
    half2v lo = cvt_pk_h2(a, b);
    half2v hi = cvt_pk_h2(c, d);
    return __builtin_shufflevector(lo, hi, 0, 1, 2, 3);
}

__device__ __forceinline__ half4v act4(float4v d) {
    return tanh_pk4(pk4_from_f32(d[0], d[1], d[2], d[3]));
}

// Pack the 3 forcing series into an interleaved float4 table in d_ws.
__global__ __launch_bounds__(BLOCK) void pack_forcings_kernel(
    const float* __restrict__ precp_s, const float* __restrict__ temp_s,
    const float* __restrict__ lday_s, float4* __restrict__ F, int T)
{
    int i = blockIdx.x * BLOCK + threadIdx.x;
    if (i < T) F[i] = make_float4(precp_s[i], temp_s[i], lday_s[i], 0.0f);
}

// MFMA 16x16x16 f16, swapped orientation: D = W^T . X  (cols = points).
//   A: lane holds A[m = lane&15][k = 4*(lane>>4)+j]
//   B: lane holds B[k = 4*(lane>>4)+j][c = lane&15]
//   D: lane holds D[r = 4*(lane>>4)+reg][c = lane&15]
// D rows == next B's k's -> layers chain shuffle-free. Layer-3 weight rows
// REPLICATED so every lane's d3[0] = out(col); pickup is cndmask-only.
// Each wave processes PPT*64 points (more independent chains -> latency hiding;
// per-wave weight-fragment build amortized).
__global__ __launch_bounds__(BLOCK, 4) void exphydro_mfma_kernel(
    const float* __restrict__ t, const float* __restrict__ S_snow,
    const float* __restrict__ S_water,
    const float4* __restrict__ F,
    const float* __restrict__ etW1, const float* __restrict__ etb1,
    const float* __restrict__ etW2, const float* __restrict__ etb2,
    const float* __restrict__ etW3, const float* __restrict__ etb3,
    const float* __restrict__ qW1, const float* __restrict__ qb1,
    const float* __restrict__ qW2, const float* __restrict__ qb2,
    const float* __restrict__ qW3, const float* __restrict__ qb3,
    const float* __restrict__ pDf, const float* __restrict__ pTmax,
    const float* __restrict__ pTmin,
    float* __restrict__ out, int N, int T)
{
    const int lane = threadIdx.x & 63;
    const int hi   = lane >> 4;
    const int m    = lane & 15;
    const int wave = threadIdx.x >> 6;
    const int base = blockIdx.x * (BLOCK * PPT) + wave * (64 * PPT);

    // ---------- A-fragments (weights, transposed), fp16 ----------
    half4v A1et, A1q, A2et, A2q, A3et, A3q;
    float4v C2et, C2q, C3et, C3q;
    #pragma unroll
    for (int j = 0; j < 4; j++) {
        int k = 4 * hi + j;
        float w1e = (k < 3) ? etW1[k * 16 + m] : ((k == 3) ? etb1[m] : 0.0f);
        float w1q = (k < 2) ? qW1 [k * 16 + m] : ((k == 2) ? qb1 [m] : 0.0f);
        A1et[j] = (_Float16)w1e;
        A1q [j] = (_Float16)w1q;
        A2et[j] = (_Float16)etW2[k * 16 + m];
        A2q [j] = (_Float16)qW2 [k * 16 + m];
        A3et[j] = (_Float16)etW3[k];     // replicated over all rows m
        A3q [j] = (_Float16)qW3 [k];
        C2et[j] = etb2[4 * hi + j];
        C2q [j] = qb2 [4 * hi + j];
        C3et[j] = etb3[0];
        C3q [j] = qb3 [0];
    }

    const float Df   = pDf[0];
    const float Tmax = pTmax[0];
    const float Tmin = pTmin[0];
    const float tmaxf = (float)(T - 1);
    const int   imax  = T - 2;

    // ---------- per-point loads + forcing interpolation (f32), PPT points ----------
    int   pp[PPT];
    float ssnow[PPT], swat[PPT], temp[PPT], precp[PPT], lday[PPT];
    int   i01[PPT], i23[PPT];
    #pragma unroll
    for (int u = 0; u < PPT; u++) {
        int p  = base + u * 64 + lane;
        int pc = (p < N) ? p : (N - 1);
        pp[u] = p;
        float tv = t[pc];
        ssnow[u] = S_snow[pc];
        swat [u] = S_water[pc];

        float tc = fminf(fmaxf(tv, 0.0f), tmaxf);
        int i0 = (int)tc;
        i0 = (i0 > imax) ? imax : i0;
        float fr = tc - (float)i0;
        float4 f0 = F[i0];
        float4 f1 = F[i0 + 1];
        precp[u] = fmaf(fr, f1.x - f0.x, f0.x);
        temp [u] = fmaf(fr, f1.y - f0.y, f0.y);
        lday [u] = fmaf(fr, f1.z - f0.z, f0.z);

        i01[u] = __builtin_bit_cast(int, cvt_pk_h2(ssnow[u], swat[u]));
        i23[u] = __builtin_bit_cast(int, cvt_pk_h2(temp[u],  precp[u]));
    }

    // ---------- MLPs via chained MFMA, PPT*4 groups of 16 points ----------
    const float4v zero4 = {0.0f, 0.0f, 0.0f, 0.0f};
    const _Float16 oneh = (_Float16)1.0f;
    const _Float16 zerh = (_Float16)0.0f;
    float etv[4 * PPT], qv[4 * PPT];

    #pragma unroll
    for (int g = 0; g < 4 * PPT; g++) {
        const int u   = g >> 2;                 // point-set
        const int src = ((g & 3) << 4) | m;     // owner lane within set
        int j01 = __shfl(i01[u], src, 64);
        int j23 = __shfl(i23[u], src, 64);
        half2v a01 = __builtin_bit_cast(half2v, j01);   // (ssnow, swat)
        half2v a23 = __builtin_bit_cast(half2v, j23);   // (temp, precp)

        half4v B1et = {a01[0], a01[1], a23[0], oneh};   // ss, sw, tp, 1
        half4v B1q  = {a01[1], a23[1], oneh,  zerh};    // sw, pr, 1, 0

        float4v d1e = __builtin_amdgcn_mfma_f32_16x16x16f16(A1et, B1et, zero4, 0, 0, 0);
        float4v d1q = __builtin_amdgcn_mfma_f32_16x16x16f16(A1q,  B1q,  zero4, 0, 0, 0);

        half4v B2et = act4(d1e);
        half4v B2q  = act4(d1q);

        float4v d2e = __builtin_amdgcn_mfma_f32_16x16x16f16(A2et, B2et, C2et, 0, 0, 0);
        float4v d2q = __builtin_amdgcn_mfma_f32_16x16x16f16(A2q,  B2q,  C2q,  0, 0, 0);

        half4v B3et = act4(d2e);
        half4v B3q  = act4(d2q);

        float4v d3e = __builtin_amdgcn_mfma_f32_16x16x16f16(A3et, B3et, C3et, 0, 0, 0);
        float4v d3q = __builtin_amdgcn_mfma_f32_16x16x16f16(A3q,  B3q,  C3q,  0, 0, 0);

        etv[g] = d3e[0];
        qv [g] = d3q[0];
    }

    // ---------- pickup + physics + store, per point-set ----------
    #pragma unroll
    for (int u = 0; u < PPT; u++) {
        float e01 = (lane & 16) ? etv[4 * u + 1] : etv[4 * u + 0];
        float e23 = (lane & 16) ? etv[4 * u + 3] : etv[4 * u + 2];
        float ET  = (lane & 32) ? e23 : e01;
        float q01 = (lane & 16) ? qv[4 * u + 1] : qv[4 * u + 0];
        float q23 = (lane & 16) ? qv[4 * u + 3] : qv[4 * u + 2];
        float Q   = (lane & 32) ? q23 : q01;

        float dT = temp[u] - Tmax;
        half4v sargs = pk4_from_f32(5.0f * dT, 5.0f * ssnow[u],
                                    5.0f * (Tmin - temp[u]), 5.0f * swat[u]);
        half4v th = tanh_pk4(sargs);
        float stepA  = fmaf(0.5f, (float)th[0], 0.5f);   // step(temp - Tmax)
        float stepSn = fmaf(0.5f, (float)th[1], 0.5f);   // step(S_snow)
        float stepPs = fmaf(0.5f, (float)th[2], 0.5f);   // step(Tmin - temp)
        float sw01   = fmaf(0.5f, (float)th[3], 0.5f);   // step(S_water)

        float melt = stepA * stepSn * fminf(ssnow[u], Df * dT);
        float Ps   = stepPs * precp[u];
        float Pr   = (1.0f - stepPs) * precp[u];

        float dS1 = Ps - melt;
        float dS2 = Pr + melt - sw01 * (lday[u] * __expf(ET) + __expf(Q));

        if (pp[u] < N) {
            out[pp[u]]     = dS1;
            out[N + pp[u]] = dS2;
        }
    }
}

extern "C" void kernel_launch(void* const* d_in, const int* in_sizes, int n_in,
                              void* d_out, int out_size, void* d_ws, size_t ws_size,
                              hipStream_t stream) {
    const float* t        = (const float*)d_in[0];
    const float* S_snow   = (const float*)d_in[1];
    const float* S_water  = (const float*)d_in[2];
    const float* precp_s  = (const float*)d_in[4];
    const float* temp_s   = (const float*)d_in[5];
    const float* lday_s   = (const float*)d_in[6];
    const float* etW1     = (const float*)d_in[7];
    const float* etb1     = (const float*)d_in[8];
    const float* etW2     = (const float*)d_in[9];
    const float* etb2     = (const float*)d_in[10];
    const float* etW3     = (const float*)d_in[11];
    const float* etb3     = (const float*)d_in[12];
    const float* qW1      = (const float*)d_in[13];
    const float* qb1      = (const float*)d_in[14];
    const float* qW2      = (const float*)d_in[15];
    const float* qb2      = (const float*)d_in[16];
    const float* qW3      = (const float*)d_in[17];
    const float* qb3      = (const float*)d_in[18];
    const float* pDf      = (const float*)d_in[19];
    const float* pTmax    = (const float*)d_in[20];
    const float* pTmin    = (const float*)d_in[21];

    int N = in_sizes[0];
    int T = in_sizes[3];
    float* out = (float*)d_out;
    float4* F = (float4*)d_ws;   // T*16 bytes, fits ws

    pack_forcings_kernel<<<(T + BLOCK - 1) / BLOCK, BLOCK, 0, stream>>>(
        precp_s, temp_s, lday_s, F, T);

    int per_block = BLOCK * PPT;
    exphydro_mfma_kernel<<<(N + per_block - 1) / per_block, BLOCK, 0, stream>>>(
        t, S_snow, S_water, F,
        etW1, etb1, etW2, etb2, etW3, etb3,
        qW1, qb1, qW2, qb2, qW3, qb3,
        pDf, pTmax, pTmin, out, N, T);
}

// Round 7
// 43.137 us; speedup vs baseline: 1.5493x; 1.5493x over previous
//
#include <hip/hip_runtime.h>
#include <math.h>

#define BLOCK 256
#define PPT   2                 // points per thread (hand-unrolled, NO arrays)

typedef _Float16 half2v __attribute__((ext_vector_type(2)));
typedef _Float16 half4v __attribute__((ext_vector_type(4)));
typedef float    float4v __attribute__((ext_vector_type(4)));

__device__ __forceinline__ half2v cvt_pk_h2(float a, float b) {
    return __builtin_bit_cast(half2v, __builtin_amdgcn_cvt_pkrtz(a, b));
}

#define H4(x) {(_Float16)(x), (_Float16)(x), (_Float16)(x), (_Float16)(x)}

// Packed-fp16 tanh: odd poly t*p(t^2), deg-5 in s, fit on s in [0,9], clamp
// |x|<=3, endpoint lifted so saturated units land on exactly +-1.0.
__device__ __forceinline__ half4v tanh_pk4(half4v x) {
    const half4v c5 = H4(-3.71625e-05f);
    const half4v c4 = H4( 1.09648e-03f);
    const half4v c3 = H4(-1.288264e-02f);
    const half4v c2 = H4( 7.941906e-02f);
    const half4v c1 = H4(-3.0042735e-01f);
    const half4v c0 = H4( 9.9607644e-01f);
    const half4v hi = H4( 3.0f);
    const half4v lo = H4(-3.0f);
    half4v t = __builtin_elementwise_min(__builtin_elementwise_max(x, lo), hi);
    half4v s = t * t;
#if __has_builtin(__builtin_elementwise_fma)
    half4v p = __builtin_elementwise_fma(c5, s, c4);
    p = __builtin_elementwise_fma(p, s, c3);
    p = __builtin_elementwise_fma(p, s, c2);
    p = __builtin_elementwise_fma(p, s, c1);
    p = __builtin_elementwise_fma(p, s, c0);
#else
    half4v p = c5 * s + c4;
    p = p * s + c3;
    p = p * s + c2;
    p = p * s + c1;
    p = p * s + c0;
#endif
    return t * p;
}

__device__ __forceinline__ half4v pk4_from_f32(float a, float b, float c, float d) {
    half2v lo = cvt_pk_h2(a, b);
    half2v hi = cvt_pk_h2(c, d);
    return __builtin_shufflevector(lo, hi, 0, 1, 2, 3);
}

__device__ __forceinline__ half4v act4(float4v d) {
    return tanh_pk4(pk4_from_f32(d[0], d[1], d[2], d[3]));
}

// Pack the 3 forcing series into an interleaved float4 table in d_ws.
__global__ __launch_bounds__(BLOCK) void pack_forcings_kernel(
    const float* __restrict__ precp_s, const float* __restrict__ temp_s,
    const float* __restrict__ lday_s, float4* __restrict__ F, int T)
{
    int i = blockIdx.x * BLOCK + threadIdx.x;
    if (i < T) F[i] = make_float4(precp_s[i], temp_s[i], lday_s[i], 0.0f);
}

// MFMA 16x16x16 f16, swapped orientation: D = W^T . X  (cols = points).
// Layer chaining is shuffle-free (D rows == next B's k rows); layer-3 weights
// replicated so pickup is cndmask-only. PPT=2 -> 8 independent chains/wave.
// ALL per-point state is in NAMED scalars: round-6's arrays got promoted to
// LDS (16KB block, 1.3M bank conflicts) -- never index per-thread arrays.
__global__ __launch_bounds__(BLOCK, 4) void exphydro_mfma_kernel(
    const float* __restrict__ t, const float* __restrict__ S_snow,
    const float* __restrict__ S_water,
    const float4* __restrict__ F,
    const float* __restrict__ etW1, const float* __restrict__ etb1,
    const float* __restrict__ etW2, const float* __restrict__ etb2,
    const float* __restrict__ etW3, const float* __restrict__ etb3,
    const float* __restrict__ qW1, const float* __restrict__ qb1,
    const float* __restrict__ qW2, const float* __restrict__ qb2,
    const float* __restrict__ qW3, const float* __restrict__ qb3,
    const float* __restrict__ pDf, const float* __restrict__ pTmax,
    const float* __restrict__ pTmin,
    float* __restrict__ out, int N, int T)
{
    const int lane = threadIdx.x & 63;
    const int hi   = lane >> 4;
    const int m    = lane & 15;
    const int wave = threadIdx.x >> 6;
    const int base = blockIdx.x * (BLOCK * PPT) + wave * (64 * PPT);

    // ---------- A-fragments (weights, transposed), fp16 ----------
    half4v A1et, A1q, A2et, A2q, A3et, A3q;
    float4v C2et, C2q, C3et, C3q;
    #pragma unroll
    for (int j = 0; j < 4; j++) {
        int k = 4 * hi + j;
        float w1e = (k < 3) ? etW1[k * 16 + m] : ((k == 3) ? etb1[m] : 0.0f);
        float w1q = (k < 2) ? qW1 [k * 16 + m] : ((k == 2) ? qb1 [m] : 0.0f);
        A1et[j] = (_Float16)w1e;
        A1q [j] = (_Float16)w1q;
        A2et[j] = (_Float16)etW2[k * 16 + m];
        A2q [j] = (_Float16)qW2 [k * 16 + m];
        A3et[j] = (_Float16)etW3[k];     // replicated over all rows m
        A3q [j] = (_Float16)qW3 [k];
        C2et[j] = etb2[4 * hi + j];
        C2q [j] = qb2 [4 * hi + j];
        C3et[j] = etb3[0];
        C3q [j] = qb3 [0];
    }

    const float Df   = pDf[0];
    const float Tmax = pTmax[0];
    const float Tmin = pTmin[0];
    const float tmaxf = (float)(T - 1);
    const int   imax  = T - 2;

    // ---------- per-point loads + interp, NAMED scalars ----------
#define LOAD_POINT(U, Pv, SSv, SWv, TPv, PRv, LDv, I01v, I23v)                 \
    const int Pv = base + (U) * 64 + lane;                                     \
    float SSv, SWv, TPv, PRv, LDv; int I01v, I23v;                             \
    {                                                                          \
        int pc = (Pv < N) ? Pv : (N - 1);                                      \
        float tv = t[pc];                                                      \
        SSv = S_snow[pc];                                                      \
        SWv = S_water[pc];                                                     \
        float tc = fminf(fmaxf(tv, 0.0f), tmaxf);                              \
        int i0 = (int)tc;                                                      \
        i0 = (i0 > imax) ? imax : i0;                                          \
        float fr = tc - (float)i0;                                             \
        float4 f0 = F[i0];                                                     \
        float4 f1 = F[i0 + 1];                                                 \
        PRv = fmaf(fr, f1.x - f0.x, f0.x);                                     \
        TPv = fmaf(fr, f1.y - f0.y, f0.y);                                     \
        LDv = fmaf(fr, f1.z - f0.z, f0.z);                                     \
        I01v = __builtin_bit_cast(int, cvt_pk_h2(SSv, SWv));                   \
        I23v = __builtin_bit_cast(int, cvt_pk_h2(TPv, PRv));                   \
    }

    LOAD_POINT(0, p0, ss0, sw0, tp0, pr0, ld0, i01_0, i23_0)
    LOAD_POINT(1, p1, ss1, sw1, tp1, pr1, ld1, i01_1, i23_1)

    // ---------- MLP chains, 8 groups, straight-line ----------
    const float4v zero4 = {0.0f, 0.0f, 0.0f, 0.0f};
    const _Float16 oneh = (_Float16)1.0f;
    const _Float16 zerh = (_Float16)0.0f;

#define MLP_GROUP(I01v, I23v, G, ETv, Qv)                                      \
    float ETv, Qv;                                                             \
    {                                                                          \
        int j01 = __shfl(I01v, ((G) << 4) | m, 64);                            \
        int j23 = __shfl(I23v, ((G) << 4) | m, 64);                            \
        half2v a01 = __builtin_bit_cast(half2v, j01);                          \
        half2v a23 = __builtin_bit_cast(half2v, j23);                          \
        half4v B1et = {a01[0], a01[1], a23[0], oneh};                          \
        half4v B1q  = {a01[1], a23[1], oneh,  zerh};                           \
        float4v d1e = __builtin_amdgcn_mfma_f32_16x16x16f16(A1et, B1et, zero4, 0, 0, 0); \
        float4v d1q = __builtin_amdgcn_mfma_f32_16x16x16f16(A1q,  B1q,  zero4, 0, 0, 0); \
        half4v B2et = act4(d1e);                                               \
        half4v B2q  = act4(d1q);                                               \
        float4v d2e = __builtin_amdgcn_mfma_f32_16x16x16f16(A2et, B2et, C2et, 0, 0, 0);  \
        float4v d2q = __builtin_amdgcn_mfma_f32_16x16x16f16(A2q,  B2q,  C2q,  0, 0, 0);  \
        half4v B3et = act4(d2e);                                               \
        half4v B3q  = act4(d2q);                                               \
        float4v d3e = __builtin_amdgcn_mfma_f32_16x16x16f16(A3et, B3et, C3et, 0, 0, 0);  \
        float4v d3q = __builtin_amdgcn_mfma_f32_16x16x16f16(A3q,  B3q,  C3q,  0, 0, 0);  \
        ETv = d3e[0];                                                          \
        Qv  = d3q[0];                                                          \
    }

    MLP_GROUP(i01_0, i23_0, 0, et00, q00)
    MLP_GROUP(i01_0, i23_0, 1, et01, q01)
    MLP_GROUP(i01_0, i23_0, 2, et02, q02)
    MLP_GROUP(i01_0, i23_0, 3, et03, q03)
    MLP_GROUP(i01_1, i23_1, 0, et10, q10)
    MLP_GROUP(i01_1, i23_1, 1, et11, q11)
    MLP_GROUP(i01_1, i23_1, 2, et12, q12)
    MLP_GROUP(i01_1, i23_1, 3, et13, q13)

    // ---------- pickup + physics + store ----------
#define FINISH_POINT(Pv, SSv, SWv, TPv, PRv, LDv, E0, E1, E2, E3, Q0, Q1, Q2, Q3) \
    {                                                                          \
        float e01s = (lane & 16) ? E1 : E0;                                    \
        float e23s = (lane & 16) ? E3 : E2;                                    \
        float ET   = (lane & 32) ? e23s : e01s;                                \
        float q01s = (lane & 16) ? Q1 : Q0;                                    \
        float q23s = (lane & 16) ? Q3 : Q2;                                    \
        float Q    = (lane & 32) ? q23s : q01s;                                \
        float dT = TPv - Tmax;                                                 \
        half4v sargs = pk4_from_f32(5.0f * dT, 5.0f * SSv,                     \
                                    5.0f * (Tmin - TPv), 5.0f * SWv);          \
        half4v th = tanh_pk4(sargs);                                           \
        float stepA  = fmaf(0.5f, (float)th[0], 0.5f);                         \
        float stepSn = fmaf(0.5f, (float)th[1], 0.5f);                         \
        float stepPs = fmaf(0.5f, (float)th[2], 0.5f);                         \
        float sw01   = fmaf(0.5f, (float)th[3], 0.5f);                         \
        float melt = stepA * stepSn * fminf(SSv, Df * dT);                     \
        float Ps   = stepPs * PRv;                                             \
        float Pr   = (1.0f - stepPs) * PRv;                                    \
        float dS1 = Ps - melt;                                                 \
        float dS2 = Pr + melt - sw01 * (LDv * __expf(ET) + __expf(Q));         \
        if (Pv < N) {                                                          \
            out[Pv]     = dS1;                                                 \
            out[N + Pv] = dS2;                                                 \
        }                                                                      \
    }

    FINISH_POINT(p0, ss0, sw0, tp0, pr0, ld0, et00, et01, et02, et03, q00, q01, q02, q03)
    FINISH_POINT(p1, ss1, sw1, tp1, pr1, ld1, et10, et11, et12, et13, q10, q11, q12, q13)
}

extern "C" void kernel_launch(void* const* d_in, const int* in_sizes, int n_in,
                              void* d_out, int out_size, void* d_ws, size_t ws_size,
                              hipStream_t stream) {
    const float* t        = (const float*)d_in[0];
    const float* S_snow   = (const float*)d_in[1];
    const float* S_water  = (const float*)d_in[2];
    const float* precp_s  = (const float*)d_in[4];
    const float* temp_s   = (const float*)d_in[5];
    const float* lday_s   = (const float*)d_in[6];
    const float* etW1     = (const float*)d_in[7];
    const float* etb1     = (const float*)d_in[8];
    const float* etW2     = (const float*)d_in[9];
    const float* etb2     = (const float*)d_in[10];
    const float* etW3     = (const float*)d_in[11];
    const float* etb3     = (const float*)d_in[12];
    const float* qW1      = (const float*)d_in[13];
    const float* qb1      = (const float*)d_in[14];
    const float* qW2      = (const float*)d_in[15];
    const float* qb2      = (const float*)d_in[16];
    const float* qW3      = (const float*)d_in[17];
    const float* qb3      = (const float*)d_in[18];
    const float* pDf      = (const float*)d_in[19];
    const float* pTmax    = (const float*)d_in[20];
    const float* pTmin    = (const float*)d_in[21];

    int N = in_sizes[0];
    int T = in_sizes[3];
    float* out = (float*)d_out;
    float4* F = (float4*)d_ws;   // T*16 bytes, fits ws

    pack_forcings_kernel<<<(T + BLOCK - 1) / BLOCK, BLOCK, 0, stream>>>(
        precp_s, temp_s, lday_s, F, T);

    int per_block = BLOCK * PPT;
    exphydro_mfma_kernel<<<(N + per_block - 1) / per_block, BLOCK, 0, stream>>>(
        t, S_snow, S_water, F,
        etW1, etb1, etW2, etb2, etW3, etb3,
        qW1, qb1, qW2, qb2, qW3, qb3,
        pDf, pTmax, pTmin, out, N, T);
}

// Round 8
// 41.449 us; speedup vs baseline: 1.6124x; 1.0407x over previous
//
#include <hip/hip_runtime.h>
#include <math.h>

#define BLOCK 256
#define PPT   2                 // points per thread (hand-unrolled, NO arrays)

typedef _Float16 half2v __attribute__((ext_vector_type(2)));
typedef _Float16 half4v __attribute__((ext_vector_type(4)));
typedef float    float4v __attribute__((ext_vector_type(4)));

__device__ __forceinline__ half2v cvt_pk_h2(float a, float b) {
    return __builtin_bit_cast(half2v, __builtin_amdgcn_cvt_pkrtz(a, b));
}

// build half4 from two packed-fp16 dwords (w0 -> elems 0,1; w1 -> elems 2,3)
__device__ __forceinline__ half4v mk_h4(unsigned w0, unsigned w1) {
    uint2 u; u.x = w0; u.y = w1;
    return __builtin_bit_cast(half4v, u);
}

#define H4(x) {(_Float16)(x), (_Float16)(x), (_Float16)(x), (_Float16)(x)}

// Packed-fp16 tanh: odd poly t*p(t^2), deg-5 in s, fit on s in [0,9], clamp
// |x|<=3, endpoint lifted so saturated units land on exactly +-1.0.
__device__ __forceinline__ half4v tanh_pk4(half4v x) {
    const half4v c5 = H4(-3.71625e-05f);
    const half4v c4 = H4( 1.09648e-03f);
    const half4v c3 = H4(-1.288264e-02f);
    const half4v c2 = H4( 7.941906e-02f);
    const half4v c1 = H4(-3.0042735e-01f);
    const half4v c0 = H4( 9.9607644e-01f);
    const half4v hi = H4( 3.0f);
    const half4v lo = H4(-3.0f);
    half4v t = __builtin_elementwise_min(__builtin_elementwise_max(x, lo), hi);
    half4v s = t * t;
#if __has_builtin(__builtin_elementwise_fma)
    half4v p = __builtin_elementwise_fma(c5, s, c4);
    p = __builtin_elementwise_fma(p, s, c3);
    p = __builtin_elementwise_fma(p, s, c2);
    p = __builtin_elementwise_fma(p, s, c1);
    p = __builtin_elementwise_fma(p, s, c0);
#else
    half4v p = c5 * s + c4;
    p = p * s + c3;
    p = p * s + c2;
    p = p * s + c1;
    p = p * s + c0;
#endif
    return t * p;
}

__device__ __forceinline__ half4v pk4_from_f32(float a, float b, float c, float d) {
    half2v lo = cvt_pk_h2(a, b);
    half2v hi = cvt_pk_h2(c, d);
    return __builtin_shufflevector(lo, hi, 0, 1, 2, 3);
}

__device__ __forceinline__ half4v act4(float4v d) {
    return tanh_pk4(pk4_from_f32(d[0], d[1], d[2], d[3]));
}

// Pack the 3 forcing series into an interleaved float4 table in d_ws.
__global__ __launch_bounds__(BLOCK) void pack_forcings_kernel(
    const float* __restrict__ precp_s, const float* __restrict__ temp_s,
    const float* __restrict__ lday_s, float4* __restrict__ F, int T)
{
    int i = blockIdx.x * BLOCK + threadIdx.x;
    if (i < T) F[i] = make_float4(precp_s[i], temp_s[i], lday_s[i], 0.0f);
}

#define MFMA16(A, B, C) __builtin_amdgcn_mfma_f32_16x16x16f16((A), (B), (C), 0, 0, 0)

// MFMA 16x16x16 f16, swapped orientation: D = W^T . X  (cols = points).
// Layer chaining is shuffle-free (D rows == next B's k rows); layer-3 weights
// replicated so pickup is cndmask-only. PPT=2, STAGE-MAJOR order: all shfls,
// then all L1 MFMAs, then all acts, ... -> 8 independent streams per stage so
// MFMA/bpermute latency hides in-wave. All state in NAMED scalars (r6: arrays
// get promoted to LDS -> 1.3M bank conflicts).
__global__ __launch_bounds__(BLOCK, 4) void exphydro_mfma_kernel(
    const float* __restrict__ t, const float* __restrict__ S_snow,
    const float* __restrict__ S_water,
    const float4* __restrict__ F,
    const float* __restrict__ etW1, const float* __restrict__ etb1,
    const float* __restrict__ etW2, const float* __restrict__ etb2,
    const float* __restrict__ etW3, const float* __restrict__ etb3,
    const float* __restrict__ qW1, const float* __restrict__ qb1,
    const float* __restrict__ qW2, const float* __restrict__ qb2,
    const float* __restrict__ qW3, const float* __restrict__ qb3,
    const float* __restrict__ pDf, const float* __restrict__ pTmax,
    const float* __restrict__ pTmin,
    float* __restrict__ out, int N, int T)
{
    const int lane = threadIdx.x & 63;
    const int hi   = lane >> 4;
    const int m    = lane & 15;
    const int wave = threadIdx.x >> 6;
    const int base = blockIdx.x * (BLOCK * PPT) + wave * (64 * PPT);

    // ---------- A-fragments (weights, transposed), fp16 ----------
    half4v A1et, A1q, A2et, A2q, A3et, A3q;
    float4v C2et, C2q, C3et, C3q;
    #pragma unroll
    for (int j = 0; j < 4; j++) {
        int k = 4 * hi + j;
        float w1e = (k < 3) ? etW1[k * 16 + m] : ((k == 3) ? etb1[m] : 0.0f);
        float w1q = (k < 2) ? qW1 [k * 16 + m] : ((k == 2) ? qb1 [m] : 0.0f);
        A1et[j] = (_Float16)w1e;
        A1q [j] = (_Float16)w1q;
        A2et[j] = (_Float16)etW2[k * 16 + m];
        A2q [j] = (_Float16)qW2 [k * 16 + m];
        A3et[j] = (_Float16)etW3[k];     // replicated over all rows m
        A3q [j] = (_Float16)qW3 [k];
        C2et[j] = etb2[4 * hi + j];
        C2q [j] = qb2 [4 * hi + j];
        C3et[j] = etb3[0];
        C3q [j] = qb3 [0];
    }

    const float Df   = pDf[0];
    const float Tmax = pTmax[0];
    const float Tmin = pTmin[0];
    const float tmaxf = (float)(T - 1);
    const int   imax  = T - 2;

    // ---------- per-point loads + interp, NAMED scalars ----------
#define LOAD_POINT(U, Pv, SSv, SWv, TPv, PRv, LDv, I01v, I23v)                 \
    const int Pv = base + (U) * 64 + lane;                                     \
    float SSv, SWv, TPv, PRv, LDv; unsigned I01v, I23v;                        \
    {                                                                          \
        int pc = (Pv < N) ? Pv : (N - 1);                                      \
        float tv = t[pc];                                                      \
        SSv = S_snow[pc];                                                      \
        SWv = S_water[pc];                                                     \
        float tc = fminf(fmaxf(tv, 0.0f), tmaxf);                              \
        int i0 = (int)tc;                                                      \
        i0 = (i0 > imax) ? imax : i0;                                          \
        float fr = tc - (float)i0;                                             \
        float4 f0 = F[i0];                                                     \
        float4 f1 = F[i0 + 1];                                                 \
        PRv = fmaf(fr, f1.x - f0.x, f0.x);                                     \
        TPv = fmaf(fr, f1.y - f0.y, f0.y);                                     \
        LDv = fmaf(fr, f1.z - f0.z, f0.z);                                     \
        I01v = __builtin_bit_cast(unsigned, cvt_pk_h2(SSv, SWv));              \
        I23v = __builtin_bit_cast(unsigned, cvt_pk_h2(TPv, PRv));              \
    }

    LOAD_POINT(0, p0, ss0, sw0, tp0, pr0, ld0, i01_0, i23_0)
    LOAD_POINT(1, p1, ss1, sw1, tp1, pr1, ld1, i01_1, i23_1)

    const float4v zero4 = {0.0f, 0.0f, 0.0f, 0.0f};

    // ---------- stage-major MLP for one point-set (4 groups breadth-first) ----
    // B1et = {ss,sw,tp,1}: w0 = i01 (ss,sw), w1 = (i23.lo16=tp) | 1.0h<<16
    // B1q  = {sw,pr,1,0}: w0 = (i01>>16=sw) | (i23.hi16=pr), w1 = 1.0h
#define MLP_SET(I01v, I23v, E0, E1, E2, E3, Q0, Q1, Q2, Q3)                    \
    float E0, E1, E2, E3, Q0, Q1, Q2, Q3;                                      \
    {                                                                          \
        /* stage: shuffles (8 independent) */                                  \
        unsigned j01_0 = (unsigned)__shfl((int)I01v, (0 << 4) | m, 64);        \
        unsigned j23_0 = (unsigned)__shfl((int)I23v, (0 << 4) | m, 64);        \
        unsigned j01_1 = (unsigned)__shfl((int)I01v, (1 << 4) | m, 64);        \
        unsigned j23_1 = (unsigned)__shfl((int)I23v, (1 << 4) | m, 64);        \
        unsigned j01_2 = (unsigned)__shfl((int)I01v, (2 << 4) | m, 64);        \
        unsigned j23_2 = (unsigned)__shfl((int)I23v, (2 << 4) | m, 64);        \
        unsigned j01_3 = (unsigned)__shfl((int)I01v, (3 << 4) | m, 64);        \
        unsigned j23_3 = (unsigned)__shfl((int)I23v, (3 << 4) | m, 64);        \
        /* stage: L1 MFMAs (8 independent) */                                  \
        float4v d1e0 = MFMA16(A1et, mk_h4(j01_0, 0x3C000000u | (j23_0 & 0xFFFFu)), zero4); \
        float4v d1q0 = MFMA16(A1q,  mk_h4((j01_0 >> 16) | (j23_0 & 0xFFFF0000u), 0x3C00u), zero4); \
        float4v d1e1 = MFMA16(A1et, mk_h4(j01_1, 0x3C000000u | (j23_1 & 0xFFFFu)), zero4); \
        float4v d1q1 = MFMA16(A1q,  mk_h4((j01_1 >> 16) | (j23_1 & 0xFFFF0000u), 0x3C00u), zero4); \
        float4v d1e2 = MFMA16(A1et, mk_h4(j01_2, 0x3C000000u | (j23_2 & 0xFFFFu)), zero4); \
        float4v d1q2 = MFMA16(A1q,  mk_h4((j01_2 >> 16) | (j23_2 & 0xFFFF0000u), 0x3C00u), zero4); \
        float4v d1e3 = MFMA16(A1et, mk_h4(j01_3, 0x3C000000u | (j23_3 & 0xFFFFu)), zero4); \
        float4v d1q3 = MFMA16(A1q,  mk_h4((j01_3 >> 16) | (j23_3 & 0xFFFF0000u), 0x3C00u), zero4); \
        /* stage: activations (8 independent) */                               \
        half4v b2e0 = act4(d1e0);  half4v b2q0 = act4(d1q0);                   \
        half4v b2e1 = act4(d1e1);  half4v b2q1 = act4(d1q1);                   \
        half4v b2e2 = act4(d1e2);  half4v b2q2 = act4(d1q2);                   \
        half4v b2e3 = act4(d1e3);  half4v b2q3 = act4(d1q3);                   \
        /* stage: L2 MFMAs */                                                  \
        float4v d2e0 = MFMA16(A2et, b2e0, C2et);  float4v d2q0 = MFMA16(A2q, b2q0, C2q); \
        float4v d2e1 = MFMA16(A2et, b2e1, C2et);  float4v d2q1 = MFMA16(A2q, b2q1, C2q); \
        float4v d2e2 = MFMA16(A2et, b2e2, C2et);  float4v d2q2 = MFMA16(A2q, b2q2, C2q); \
        float4v d2e3 = MFMA16(A2et, b2e3, C2et);  float4v d2q3 = MFMA16(A2q, b2q3, C2q); \
        /* stage: activations */                                               \
        half4v b3e0 = act4(d2e0);  half4v b3q0 = act4(d2q0);                   \
        half4v b3e1 = act4(d2e1);  half4v b3q1 = act4(d2q1);                   \
        half4v b3e2 = act4(d2e2);  half4v b3q2 = act4(d2q2);                   \
        half4v b3e3 = act4(d2e3);  half4v b3q3 = act4(d2q3);                   \
        /* stage: L3 MFMAs */                                                  \
        float4v d3e0 = MFMA16(A3et, b3e0, C3et);  float4v d3q0 = MFMA16(A3q, b3q0, C3q); \
        float4v d3e1 = MFMA16(A3et, b3e1, C3et);  float4v d3q1 = MFMA16(A3q, b3q1, C3q); \
        float4v d3e2 = MFMA16(A3et, b3e2, C3et);  float4v d3q2 = MFMA16(A3q, b3q2, C3q); \
        float4v d3e3 = MFMA16(A3et, b3e3, C3et);  float4v d3q3 = MFMA16(A3q, b3q3, C3q); \
        E0 = d3e0[0]; E1 = d3e1[0]; E2 = d3e2[0]; E3 = d3e3[0];                \
        Q0 = d3q0[0]; Q1 = d3q1[0]; Q2 = d3q2[0]; Q3 = d3q3[0];                \
    }

    MLP_SET(i01_0, i23_0, et00, et01, et02, et03, q00, q01, q02, q03)
    MLP_SET(i01_1, i23_1, et10, et11, et12, et13, q10, q11, q12, q13)

    // ---------- pickup + physics + store ----------
#define FINISH_POINT(Pv, SSv, SWv, TPv, PRv, LDv, E0, E1, E2, E3, Q0, Q1, Q2, Q3) \
    {                                                                          \
        float e01s = (lane & 16) ? E1 : E0;                                    \
        float e23s = (lane & 16) ? E3 : E2;                                    \
        float ET   = (lane & 32) ? e23s : e01s;                                \
        float q01s = (lane & 16) ? Q1 : Q0;                                    \
        float q23s = (lane & 16) ? Q3 : Q2;                                    \
        float Q    = (lane & 32) ? q23s : q01s;                                \
        float dT = TPv - Tmax;                                                 \
        half4v sargs = pk4_from_f32(5.0f * dT, 5.0f * SSv,                     \
                                    5.0f * (Tmin - TPv), 5.0f * SWv);          \
        half4v th = tanh_pk4(sargs);                                           \
        float stepA  = fmaf(0.5f, (float)th[0], 0.5f);                         \
        float stepSn = fmaf(0.5f, (float)th[1], 0.5f);                         \
        float stepPs = fmaf(0.5f, (float)th[2], 0.5f);                         \
        float sw01   = fmaf(0.5f, (float)th[3], 0.5f);                         \
        float melt = stepA * stepSn * fminf(SSv, Df * dT);                     \
        float Ps   = stepPs * PRv;                                             \
        float Pr   = (1.0f - stepPs) * PRv;                                    \
        float dS1 = Ps - melt;                                                 \
        float dS2 = Pr + melt - sw01 * (LDv * __expf(ET) + __expf(Q));         \
        if (Pv < N) {                                                          \
            out[Pv]     = dS1;                                                 \
            out[N + Pv] = dS2;                                                 \
        }                                                                      \
    }

    FINISH_POINT(p0, ss0, sw0, tp0, pr0, ld0, et00, et01, et02, et03, q00, q01, q02, q03)
    FINISH_POINT(p1, ss1, sw1, tp1, pr1, ld1, et10, et11, et12, et13, q10, q11, q12, q13)
}

extern "C" void kernel_launch(void* const* d_in, const int* in_sizes, int n_in,
                              void* d_out, int out_size, void* d_ws, size_t ws_size,
                              hipStream_t stream) {
    const float* t        = (const float*)d_in[0];
    const float* S_snow   = (const float*)d_in[1];
    const float* S_water  = (const float*)d_in[2];
    const float* precp_s  = (const float*)d_in[4];
    const float* temp_s   = (const float*)d_in[5];
    const float* lday_s   = (const float*)d_in[6];
    const float* etW1     = (const float*)d_in[7];
    const float* etb1     = (const float*)d_in[8];
    const float* etW2     = (const float*)d_in[9];
    const float* etb2     = (const float*)d_in[10];
    const float* etW3     = (const float*)d_in[11];
    const float* etb3     = (const float*)d_in[12];
    const float* qW1      = (const float*)d_in[13];
    const float* qb1      = (const float*)d_in[14];
    const float* qW2      = (const float*)d_in[15];
    const float* qb2      = (const float*)d_in[16];
    const float* qW3      = (const float*)d_in[17];
    const float* qb3      = (const float*)d_in[18];
    const float* pDf      = (const float*)d_in[19];
    const float* pTmax    = (const float*)d_in[20];
    const float* pTmin    = (const float*)d_in[21];

    int N = in_sizes[0];
    int T = in_sizes[3];
    float* out = (float*)d_out;
    float4* F = (float4*)d_ws;   // T*16 bytes, fits ws

    pack_forcings_kernel<<<(T + BLOCK - 1) / BLOCK, BLOCK, 0, stream>>>(
        precp_s, temp_s, lday_s, F, T);

    int per_block = BLOCK * PPT;
    exphydro_mfma_kernel<<<(N + per_block - 1) / per_block, BLOCK, 0, stream>>>(
        t, S_snow, S_water, F,
        etW1, etb1, etW2, etb2, etW3, etb3,
        qW1, qb1, qW2, qb2, qW3, qb3,
        pDf, pTmax, pTmin, out, N, T);
}